// Round 1
// baseline (216.745 us; speedup 1.0000x reference)
//
#include <hip/hip_runtime.h>

#define B_ROWS 16384
#define D_DIM  256
#define C_CLS  4096
#define CLAMP_LO 1e-12f
#define CLAMP_HI 1e12f

__device__ __forceinline__ float wave_reduce_sum(float v) {
    // full 64-lane wave reduction
    for (int o = 32; o > 0; o >>= 1) v += __shfl_xor(v, o, 64);
    return v;
}

// K1: per-row scatter-add into per-class sums + counts; track first available class.
__global__ void __launch_bounds__(256) k_accum(const float* __restrict__ x,
                                               const int* __restrict__ labels,
                                               float* __restrict__ sums,
                                               int* __restrict__ counts,
                                               int* __restrict__ firstCls) {
    const int b = blockIdx.x;
    const int c = labels[b];
    const float v = x[(size_t)b * D_DIM + threadIdx.x];
    atomicAdd(&sums[(size_t)c * D_DIM + threadIdx.x], v);
    if (threadIdx.x == 0) {
        atomicAdd(&counts[c], 1);
        atomicMin(firstCls, c);
    }
}

// K2: one wave per row: d2 = ||x||^2 + ||nc||^2 - 2 x.nc at c = labels[b];
// nc recomputed on the fly from sums/centers. Accumulate clamped d2 per class.
__global__ void __launch_bounds__(256) k_dist(const float* __restrict__ x,
                                              const int* __restrict__ labels,
                                              const float* __restrict__ centers,
                                              const float* __restrict__ sums,
                                              const int* __restrict__ counts,
                                              const int* __restrict__ firstCls,
                                              float* __restrict__ Sclass) {
    const int wave = threadIdx.x >> 6;
    const int lane = threadIdx.x & 63;
    const int b = blockIdx.x * 4 + wave;
    const int c = labels[b];
    const int cnt = counts[c];          // >= 1 by construction (this row has label c)
    const int first = *firstCls;
    const float inv = 1.0f / (float)cnt;

    const float4 xv = *reinterpret_cast<const float4*>(x       + (size_t)b * D_DIM + lane * 4);
    const float4 sv = *reinterpret_cast<const float4*>(sums    + (size_t)c * D_DIM + lane * 4);
    const float4 cv = *reinterpret_cast<const float4*>(centers + (size_t)c * D_DIM + lane * 4);

    float m0 = sv.x * inv, m1 = sv.y * inv, m2 = sv.z * inv, m3 = sv.w * inv;
    float n0, n1, n2, n3;
    if (c == first) {
        n0 = m0; n1 = m1; n2 = m2; n3 = m3;
    } else {
        n0 = 0.5f * cv.x + 0.5f * m0;
        n1 = 0.5f * cv.y + 0.5f * m1;
        n2 = 0.5f * cv.z + 0.5f * m2;
        n3 = 0.5f * cv.w + 0.5f * m3;
    }

    float xx = xv.x * xv.x + xv.y * xv.y + xv.z * xv.z + xv.w * xv.w;
    float nn = n0 * n0 + n1 * n1 + n2 * n2 + n3 * n3;
    float xn = xv.x * n0 + xv.y * n1 + xv.z * n2 + xv.w * n3;

    xx = wave_reduce_sum(xx);
    nn = wave_reduce_sum(nn);
    xn = wave_reduce_sum(xn);

    if (lane == 0) {
        float d2 = xx + nn - 2.0f * xn;
        d2 = fminf(fmaxf(d2, CLAMP_LO), CLAMP_HI);
        atomicAdd(&Sclass[c], d2);
    }
}

// K3: final reduce over classes.
__global__ void __launch_bounds__(256) k_final(const float* __restrict__ Sclass,
                                               const int* __restrict__ counts,
                                               float* __restrict__ out) {
    float acc = 0.0f;
    for (int c = threadIdx.x; c < C_CLS; c += 256) {
        const int cnt = counts[c];
        const float denom = (float)max(cnt, 1);
        // off-diagonal (masked-out) entries all clip to 1e-12
        acc += (Sclass[c] + (float)(B_ROWS - cnt) * CLAMP_LO) / denom;
    }
    __shared__ float red[4];
    acc = wave_reduce_sum(acc);
    if ((threadIdx.x & 63) == 0) red[threadIdx.x >> 6] = acc;
    __syncthreads();
    if (threadIdx.x == 0) {
        float t = red[0] + red[1] + red[2] + red[3];
        out[0] = t / (float)((size_t)C_CLS * D_DIM);
    }
}

extern "C" void kernel_launch(void* const* d_in, const int* in_sizes, int n_in,
                              void* d_out, int out_size, void* d_ws, size_t ws_size,
                              hipStream_t stream) {
    const float* x       = (const float*)d_in[0];
    const float* centers = (const float*)d_in[1];
    const int*   labels  = (const int*)d_in[2];
    float* out = (float*)d_out;

    char* ws = (char*)d_ws;
    const size_t sums_bytes   = (size_t)C_CLS * D_DIM * sizeof(float); // 4 MiB
    float* sums    = (float*)ws;
    int*   counts  = (int*)(ws + sums_bytes);
    float* Sclass  = (float*)(ws + sums_bytes + (size_t)C_CLS * sizeof(int));
    int*   firstCls = (int*)(ws + sums_bytes + 2 * (size_t)C_CLS * sizeof(int));

    const size_t zero_bytes = sums_bytes + 2 * (size_t)C_CLS * sizeof(int);
    hipMemsetAsync(d_ws, 0, zero_bytes, stream);
    hipMemsetAsync(ws + zero_bytes, 0x7F, sizeof(int), stream); // firstCls = big

    k_accum<<<B_ROWS, 256, 0, stream>>>(x, labels, sums, counts, firstCls);
    k_dist<<<B_ROWS / 4, 256, 0, stream>>>(x, labels, centers, sums, counts, firstCls, Sclass);
    k_final<<<1, 256, 0, stream>>>(Sclass, counts, out);
}

// Round 2
// 40.791 us; speedup vs baseline: 5.3135x; 5.3135x over previous
//
#include <hip/hip_runtime.h>

#define B_ROWS 16384
#define D_DIM  256
#define C_CLS  4096
#define CLAMP_LO 1e-12f
#define CLAMP_HI 1e12f

__device__ __forceinline__ float wave_reduce_sum(float v) {
    for (int o = 32; o > 0; o >>= 1) v += __shfl_xor(v, o, 64);
    return v;
}
__device__ __forceinline__ int wave_reduce_min(int v) {
    for (int o = 32; o > 0; o >>= 1) v = min(v, __shfl_xor(v, o, 64));
    return v;
}

// K1: histogram of labels + first (min) occupied class. 16K int atomics total.
__global__ void __launch_bounds__(256) k_count(const int* __restrict__ labels,
                                               int* __restrict__ counts,
                                               int* __restrict__ firstCls) {
    const int b = blockIdx.x * 256 + threadIdx.x;
    const int c = labels[b];
    atomicAdd(&counts[c], 1);
    int m = wave_reduce_min(c);
    __shared__ int red[4];
    if ((threadIdx.x & 63) == 0) red[threadIdx.x >> 6] = m;
    __syncthreads();
    if (threadIdx.x == 0) {
        int mm = min(min(red[0], red[1]), min(red[2], red[3]));
        atomicMin(firstCls, mm);
    }
}

// K2: exclusive scan of counts -> offsets (and a mutable cursor copy).
__global__ void __launch_bounds__(1024) k_scan(const int* __restrict__ counts,
                                               int* __restrict__ offsets,
                                               int* __restrict__ cursor) {
    __shared__ int part[1024];
    const int t = threadIdx.x;
    const int base = t * 4;
    const int c0 = counts[base], c1 = counts[base + 1],
              c2 = counts[base + 2], c3 = counts[base + 3];
    const int s = c0 + c1 + c2 + c3;
    part[t] = s;
    __syncthreads();
    for (int off = 1; off < 1024; off <<= 1) {
        int v = 0;
        if (t >= off) v = part[t - off];
        __syncthreads();
        if (t >= off) part[t] += v;
        __syncthreads();
    }
    const int excl = part[t] - s;
    const int o0 = excl, o1 = o0 + c0, o2 = o1 + c1, o3 = o2 + c2;
    offsets[base] = o0; offsets[base + 1] = o1;
    offsets[base + 2] = o2; offsets[base + 3] = o3;
    cursor[base] = o0; cursor[base + 1] = o1;
    cursor[base + 2] = o2; cursor[base + 3] = o3;
}

// K3: scatter row indices into per-class buckets.
__global__ void __launch_bounds__(256) k_scatter(const int* __restrict__ labels,
                                                 int* __restrict__ cursor,
                                                 int* __restrict__ bucket) {
    const int b = blockIdx.x * 256 + threadIdx.x;
    const int c = labels[b];
    const int pos = atomicAdd(&cursor[c], 1);
    bucket[pos] = b;
}

// K4: one block per class. Pass 1: direct sum of member rows (registers).
// Then nc; pass 2: per-row clamped distance, block-reduced. No float atomics.
__global__ void __launch_bounds__(256) k_class(const float* __restrict__ x,
                                               const float* __restrict__ centers,
                                               const int* __restrict__ bucket,
                                               const int* __restrict__ offsets,
                                               const int* __restrict__ counts,
                                               const int* __restrict__ firstCls,
                                               float* __restrict__ Sclass) {
    const int c = blockIdx.x;
    const int t = threadIdx.x;
    const int cnt = counts[c];
    if (cnt == 0) {
        if (t == 0) Sclass[c] = 0.0f;
        return;
    }
    const int off = offsets[c];
    float s = 0.0f;
    for (int i = 0; i < cnt; ++i) {
        const int b = bucket[off + i];
        s += x[(size_t)b * D_DIM + t];
    }
    const float mean = s / (float)cnt;
    const float nc = (c == *firstCls)
                         ? mean
                         : 0.5f * centers[(size_t)c * D_DIM + t] + 0.5f * mean;

    __shared__ float red[4];
    float total = 0.0f;
    for (int i = 0; i < cnt; ++i) {
        const int b = bucket[off + i];
        const float diff = x[(size_t)b * D_DIM + t] - nc;
        float d = wave_reduce_sum(diff * diff);
        if ((t & 63) == 0) red[t >> 6] = d;
        __syncthreads();
        const float d2 = red[0] + red[1] + red[2] + red[3];
        if (t == 0) total += fminf(fmaxf(d2, CLAMP_LO), CLAMP_HI);
        __syncthreads();
    }
    if (t == 0) Sclass[c] = total;
}

// K5: final reduce over classes.
__global__ void __launch_bounds__(256) k_final(const float* __restrict__ Sclass,
                                               const int* __restrict__ counts,
                                               float* __restrict__ out) {
    float acc = 0.0f;
    for (int c = threadIdx.x; c < C_CLS; c += 256) {
        const int cnt = counts[c];
        const float denom = (float)max(cnt, 1);
        acc += (Sclass[c] + (float)(B_ROWS - cnt) * CLAMP_LO) / denom;
    }
    __shared__ float red[4];
    acc = wave_reduce_sum(acc);
    if ((threadIdx.x & 63) == 0) red[threadIdx.x >> 6] = acc;
    __syncthreads();
    if (threadIdx.x == 0) {
        float t = red[0] + red[1] + red[2] + red[3];
        out[0] = t / (float)((size_t)C_CLS * D_DIM);
    }
}

extern "C" void kernel_launch(void* const* d_in, const int* in_sizes, int n_in,
                              void* d_out, int out_size, void* d_ws, size_t ws_size,
                              hipStream_t stream) {
    const float* x       = (const float*)d_in[0];
    const float* centers = (const float*)d_in[1];
    const int*   labels  = (const int*)d_in[2];
    float* out = (float*)d_out;

    char* ws = (char*)d_ws;
    int*   counts   = (int*)ws;                                  // 4096
    int*   offsets  = (int*)(ws + 1 * C_CLS * sizeof(int));      // 4096
    int*   cursor   = (int*)(ws + 2 * C_CLS * sizeof(int));      // 4096
    float* Sclass   = (float*)(ws + 3 * C_CLS * sizeof(int));    // 4096
    int*   bucket   = (int*)(ws + 4 * C_CLS * sizeof(int));      // 16384
    int*   firstCls = (int*)(ws + 4 * C_CLS * sizeof(int) + B_ROWS * sizeof(int));

    hipMemsetAsync(counts, 0, C_CLS * sizeof(int), stream);
    hipMemsetAsync(firstCls, 0x7F, sizeof(int), stream);

    k_count  <<<B_ROWS / 256, 256, 0, stream>>>(labels, counts, firstCls);
    k_scan   <<<1, 1024, 0, stream>>>(counts, offsets, cursor);
    k_scatter<<<B_ROWS / 256, 256, 0, stream>>>(labels, cursor, bucket);
    k_class  <<<C_CLS, 256, 0, stream>>>(x, centers, bucket, offsets, counts,
                                         firstCls, Sclass);
    k_final  <<<1, 256, 0, stream>>>(Sclass, counts, out);
}

// Round 3
// 28.228 us; speedup vs baseline: 7.6784x; 1.4451x over previous
//
#include <hip/hip_runtime.h>

#define B_ROWS 16384
#define D_DIM  256
#define C_CLS  4096
#define CLAMP_LO 1e-12f
#define CLAMP_HI 1e12f

__device__ __forceinline__ float wave_reduce_sum(float v) {
    for (int o = 32; o > 0; o >>= 1) v += __shfl_xor(v, o, 64);
    return v;
}
__device__ __forceinline__ int wave_reduce_min(int v) {
    for (int o = 32; o > 0; o >>= 1) v = min(v, __shfl_xor(v, o, 64));
    return v;
}

// K1: one-block counting sort of 16K labels into per-class buckets.
// Also computes counts, offsets, first occupied class. No global memsets needed.
__global__ void __launch_bounds__(1024) k_sort(const int* __restrict__ labels,
                                               int* __restrict__ bucket,
                                               int* __restrict__ offsets,
                                               int* __restrict__ counts,
                                               int* __restrict__ firstCls) {
    __shared__ int hist[C_CLS];   // histogram, then reused as scatter cursor
    __shared__ int wsum[16];
    __shared__ int firstRed;
    const int t = threadIdx.x;
    const int lane = t & 63;
    const int wv = t >> 6;

    #pragma unroll
    for (int i = 0; i < 4; ++i) hist[t + 1024 * i] = 0;
    if (t == 0) firstRed = 0x7FFFFFFF;
    __syncthreads();

    int lab[16];
    #pragma unroll
    for (int i = 0; i < 16; ++i) {
        lab[i] = labels[t + 1024 * i];
        atomicAdd(&hist[lab[i]], 1);
    }
    __syncthreads();

    // thread t owns hist[4t..4t+3]
    const int c0 = hist[4 * t], c1 = hist[4 * t + 1],
              c2 = hist[4 * t + 2], c3 = hist[4 * t + 3];
    const int s = c0 + c1 + c2 + c3;

    // first occupied class (min index with count > 0)
    int fm = 0x7FFFFFFF;
    if (c3 > 0) fm = 4 * t + 3;
    if (c2 > 0) fm = 4 * t + 2;
    if (c1 > 0) fm = 4 * t + 1;
    if (c0 > 0) fm = 4 * t;
    fm = wave_reduce_min(fm);
    if (lane == 0) atomicMin(&firstRed, fm);

    // block-wide inclusive scan of per-thread sums (shfl within wave, then wave sums)
    int incl = s;
    #pragma unroll
    for (int o = 1; o < 64; o <<= 1) {
        int u = __shfl_up(incl, o, 64);
        if (lane >= o) incl += u;
    }
    if (lane == 63) wsum[wv] = incl;
    __syncthreads();
    if (wv == 0) {
        int w = (lane < 16) ? wsum[lane] : 0;
        #pragma unroll
        for (int o = 1; o < 16; o <<= 1) {
            int u = __shfl_up(w, o, 64);
            if (lane >= o) w += u;
        }
        if (lane < 16) wsum[lane] = w;
    }
    __syncthreads();
    const int base = (wv > 0) ? wsum[wv - 1] : 0;
    const int excl = base + incl - s;

    const int o0 = excl, o1 = o0 + c0, o2 = o1 + c1, o3 = o2 + c2;
    *reinterpret_cast<int4*>(&counts[4 * t])  = make_int4(c0, c1, c2, c3);
    *reinterpret_cast<int4*>(&offsets[4 * t]) = make_int4(o0, o1, o2, o3);
    if (t == 0) *firstCls = firstRed;

    // reuse hist as scatter cursor
    hist[4 * t] = o0; hist[4 * t + 1] = o1;
    hist[4 * t + 2] = o2; hist[4 * t + 3] = o3;
    __syncthreads();

    #pragma unroll
    for (int i = 0; i < 16; ++i) {
        const int pos = atomicAdd(&hist[lab[i]], 1);
        bucket[pos] = t + 1024 * i;
    }
}

// K2: one block per class, single pass over member rows.
// S_c = sum||x||^2 - 2*s.nc + cnt*||nc||^2  (same expansion the reference uses)
__global__ void __launch_bounds__(256) k_class(const float* __restrict__ x,
                                               const float* __restrict__ centers,
                                               const int* __restrict__ bucket,
                                               const int* __restrict__ offsets,
                                               const int* __restrict__ counts,
                                               const int* __restrict__ firstCls,
                                               float* __restrict__ contrib) {
    const int c = blockIdx.x;
    const int t = threadIdx.x;
    const int cnt = counts[c];
    if (cnt == 0) {
        // all B entries masked -> clamp to 1e-12, denom = 1
        if (t == 0) contrib[c] = (float)B_ROWS * CLAMP_LO;
        return;
    }
    const int off = offsets[c];

    float s = 0.0f, q = 0.0f;
    for (int i = 0; i < cnt; ++i) {
        const int b = bucket[off + i];
        const float v = x[(size_t)b * D_DIM + t];
        s += v;
        q += v * v;
    }
    const float inv = 1.0f / (float)cnt;
    const float mean = s * inv;
    const float nc = (c == *firstCls)
                         ? mean
                         : 0.5f * centers[(size_t)c * D_DIM + t] + 0.5f * mean;

    float a0 = q;        // sum of squares of members
    float a1 = s * nc;   // s . nc
    float a2 = nc * nc;  // ||nc||^2
    a0 = wave_reduce_sum(a0);
    a1 = wave_reduce_sum(a1);
    a2 = wave_reduce_sum(a2);
    __shared__ float r0[4], r1[4], r2[4];
    if ((t & 63) == 0) { r0[t >> 6] = a0; r1[t >> 6] = a1; r2[t >> 6] = a2; }
    __syncthreads();
    if (t == 0) {
        const float Q  = r0[0] + r0[1] + r0[2] + r0[3];
        const float Dt = r1[0] + r1[1] + r1[2] + r1[3];
        const float NN = r2[0] + r2[1] + r2[2] + r2[3];
        float S = Q - 2.0f * Dt + (float)cnt * NN;
        // per-row clamp can only bind at the singleton/first-class degenerate
        // case where the closed form gives exactly 0 -> matches reference
        S = fminf(fmaxf(S, CLAMP_LO), CLAMP_HI);
        contrib[c] = (S + (float)(B_ROWS - cnt) * CLAMP_LO) / (float)cnt;
    }
}

// K3: sum contributions, scale.
__global__ void __launch_bounds__(256) k_final(const float* __restrict__ contrib,
                                               float* __restrict__ out) {
    const int t = threadIdx.x;
    float acc = 0.0f;
    for (int i = t; i < C_CLS / 4; i += 256) {
        const float4 v = reinterpret_cast<const float4*>(contrib)[i];
        acc += v.x + v.y + v.z + v.w;
    }
    acc = wave_reduce_sum(acc);
    __shared__ float red[4];
    if ((t & 63) == 0) red[t >> 6] = acc;
    __syncthreads();
    if (t == 0) {
        const float total = red[0] + red[1] + red[2] + red[3];
        out[0] = total / (float)((size_t)C_CLS * D_DIM);
    }
}

extern "C" void kernel_launch(void* const* d_in, const int* in_sizes, int n_in,
                              void* d_out, int out_size, void* d_ws, size_t ws_size,
                              hipStream_t stream) {
    const float* x       = (const float*)d_in[0];
    const float* centers = (const float*)d_in[1];
    const int*   labels  = (const int*)d_in[2];
    float* out = (float*)d_out;

    char* ws = (char*)d_ws;
    int*   bucket   = (int*)ws;                                   // 16384
    int*   offsets  = (int*)(ws + B_ROWS * sizeof(int));          // 4096
    int*   counts   = (int*)(ws + (B_ROWS + C_CLS) * sizeof(int));// 4096
    float* contrib  = (float*)(ws + (B_ROWS + 2 * C_CLS) * sizeof(int)); // 4096
    int*   firstCls = (int*)(ws + (B_ROWS + 3 * C_CLS) * sizeof(int));

    k_sort <<<1, 1024, 0, stream>>>(labels, bucket, offsets, counts, firstCls);
    k_class<<<C_CLS, 256, 0, stream>>>(x, centers, bucket, offsets, counts,
                                       firstCls, contrib);
    k_final<<<1, 256, 0, stream>>>(contrib, out);
}